// Round 6
// baseline (184.210 us; speedup 1.0000x reference)
//
#include <hip/hip_runtime.h>

// Problem constants
#define BB 32
#define CC 1024
#define QQ 64
#define EE 256
#define FE 1024
#define MM (BB*CC)   // 32768

typedef __bf16 bf16_t;
typedef bf16_t bf16x8 __attribute__((ext_vector_type(8)));
typedef float f32x4 __attribute__((ext_vector_type(4)));

__device__ __forceinline__ unsigned short f2bf(float f) {
  unsigned u = __float_as_uint(f);
  u += 0x7fffu + ((u >> 16) & 1u);   // RNE
  return (unsigned short)(u >> 16);
}
__device__ __forceinline__ float bf2f(unsigned short u) {
  return __uint_as_float(((unsigned)u) << 16);
}

__device__ __forceinline__ void gload_lds16(const void* g, void* l) {
  __builtin_amdgcn_global_load_lds(
      (const __attribute__((address_space(1))) unsigned int*)g,
      (__attribute__((address_space(3))) unsigned int*)l, 16, 0, 0);
}

// ---------------------------------------------------------------- prep: qm = question*w_mult, qw = question.w_question; + cast W to bf16
__global__ void k_prep(const float* __restrict__ question, const float* __restrict__ w_question,
                       const float* __restrict__ w_multiple, float* __restrict__ qm,
                       float* __restrict__ qw,
                       const float* __restrict__ W, unsigned short* __restrict__ Wb) {
  int bx = blockIdx.x;
  if (bx < 512) {
    int gid = bx * 256 + threadIdx.x;
    int row = gid >> 6;            // (b*QQ + q), 0..2047
    int lane = gid & 63;
    const float4 q = *(const float4*)(question + (size_t)row * EE + lane * 4);
    const float4 wm = *(const float4*)(w_multiple + lane * 4);
    const float4 wq = *(const float4*)(w_question + lane * 4);
    float4 r; r.x = q.x*wm.x; r.y = q.y*wm.y; r.z = q.z*wm.z; r.w = q.w*wm.w;
    *(float4*)(qm + (size_t)row * EE + lane * 4) = r;
    float d = q.x*wq.x + q.y*wq.y + q.z*wq.z + q.w*wq.w;
    d += __shfl_xor(d, 1);  d += __shfl_xor(d, 2);  d += __shfl_xor(d, 4);
    d += __shfl_xor(d, 8);  d += __shfl_xor(d, 16); d += __shfl_xor(d, 32);
    if (lane == 0) qw[row] = d;
  } else {
    int i = ((bx - 512) * 256 + threadIdx.x) * 4;
    float4 v = *(const float4*)(W + i);
    ushort4 o; o.x = f2bf(v.x); o.y = f2bf(v.y); o.z = f2bf(v.z); o.w = f2bf(v.w);
    *(ushort4*)(Wb + i) = o;
  }
}

#define DOT4(acc, A, Bv) acc += A.x*Bv.x + A.y*Bv.y + A.z*Bv.z + A.w*Bv.w

// ---------------------------------------------------------------- similarity + softmax over q -> P, rowmax, attended block0
__launch_bounds__(256)
__global__ void k_sim(const float* __restrict__ ctx, const float* __restrict__ qm,
                      const float* __restrict__ qw_g, const float* __restrict__ w_context,
                      float* __restrict__ P, float* __restrict__ rowmax,
                      unsigned short* __restrict__ att) {
  __shared__ float qml[QQ][260];   // qm[q][e], padded
  __shared__ float ck[64][36];     // ctx chunk [c][e32]
  __shared__ float cwl[64];
  __shared__ float qwl[QQ];
  const int tid = threadIdx.x;
  const int b = blockIdx.y;
  const int c0 = blockIdx.x * 64;
  const int tx = tid & 15, ty = tid >> 4;

  const float* qmb = qm + (size_t)b * (QQ * EE);
  for (int idx = tid * 4; idx < QQ * EE; idx += 1024) {
    float4 v = *(const float4*)(qmb + idx);
    *(float4*)&qml[idx >> 8][idx & 255] = v;
  }
  if (tid < QQ) qwl[tid] = qw_g[b * QQ + tid];

  // stage 64 ctx rows: each thread owns rows cr and cr+32, elems er..er+3 per 32-chunk
  const int cr = tid >> 3, er = (tid & 7) * 4;
  const float* crow0 = ctx + ((size_t)(b * CC + c0 + cr)) * EE;
  const float* crow1 = crow0 + 32 * EE;
  unsigned short* arow0 = att + ((size_t)(b * CC + c0 + cr)) * FE;
  unsigned short* arow1 = arow0 + (size_t)32 * FE;
  float s[4][4] = {{0.f}};
  float cp0 = 0.f, cp1 = 0.f;

  for (int eo = 0; eo < EE; eo += 32) {
    float4 cv0 = *(const float4*)(crow0 + eo + er);
    float4 cv1 = *(const float4*)(crow1 + eo + er);
    float4 wc = *(const float4*)(w_context + eo + er);
    cp0 += cv0.x*wc.x + cv0.y*wc.y + cv0.z*wc.z + cv0.w*wc.w;
    cp1 += cv1.x*wc.x + cv1.y*wc.y + cv1.z*wc.z + cv1.w*wc.w;
    // write attended block0 = bf16(ctx)
    ushort4 u0, u1;
    u0.x = f2bf(cv0.x); u0.y = f2bf(cv0.y); u0.z = f2bf(cv0.z); u0.w = f2bf(cv0.w);
    u1.x = f2bf(cv1.x); u1.y = f2bf(cv1.y); u1.z = f2bf(cv1.z); u1.w = f2bf(cv1.w);
    *(ushort4*)(arow0 + eo + er) = u0;
    *(ushort4*)(arow1 + eo + er) = u1;
    __syncthreads();
    *(float4*)&ck[cr][er] = cv0;
    *(float4*)&ck[cr + 32][er] = cv1;
    __syncthreads();
#pragma unroll
    for (int ee = 0; ee < 32; ee += 4) {
      float4 a0 = *(const float4*)&ck[ty +  0][ee];
      float4 a1 = *(const float4*)&ck[ty + 16][ee];
      float4 a2 = *(const float4*)&ck[ty + 32][ee];
      float4 a3 = *(const float4*)&ck[ty + 48][ee];
      float4 b0 = *(const float4*)&qml[tx +  0][eo + ee];
      float4 b1 = *(const float4*)&qml[tx + 16][eo + ee];
      float4 b2 = *(const float4*)&qml[tx + 32][eo + ee];
      float4 b3 = *(const float4*)&qml[tx + 48][eo + ee];
      DOT4(s[0][0], a0, b0); DOT4(s[0][1], a0, b1); DOT4(s[0][2], a0, b2); DOT4(s[0][3], a0, b3);
      DOT4(s[1][0], a1, b0); DOT4(s[1][1], a1, b1); DOT4(s[1][2], a1, b2); DOT4(s[1][3], a1, b3);
      DOT4(s[2][0], a2, b0); DOT4(s[2][1], a2, b1); DOT4(s[2][2], a2, b2); DOT4(s[2][3], a2, b3);
      DOT4(s[3][0], a3, b0); DOT4(s[3][1], a3, b1); DOT4(s[3][2], a3, b2); DOT4(s[3][3], a3, b3);
    }
  }
  // reduce cw partials (8 lanes per row, consecutive)
  cp0 += __shfl_xor(cp0, 1); cp0 += __shfl_xor(cp0, 2); cp0 += __shfl_xor(cp0, 4);
  cp1 += __shfl_xor(cp1, 1); cp1 += __shfl_xor(cp1, 2); cp1 += __shfl_xor(cp1, 4);
  if ((tid & 7) == 0) { cwl[cr] = cp0; cwl[cr + 32] = cp1; }
  __syncthreads();

  // softmax per row (rows c = ty + 16i held by the 16 lanes sharing ty)
#pragma unroll
  for (int i = 0; i < 4; ++i) {
    int c = ty + 16 * i;
    float cw = cwl[c];
    float f[4], mx = -1e30f;
#pragma unroll
    for (int j = 0; j < 4; ++j) {
      f[j] = s[i][j] + cw + qwl[tx + 16 * j];
      mx = fmaxf(mx, f[j]);
    }
    mx = fmaxf(mx, __shfl_xor(mx, 1));
    mx = fmaxf(mx, __shfl_xor(mx, 2));
    mx = fmaxf(mx, __shfl_xor(mx, 4));
    mx = fmaxf(mx, __shfl_xor(mx, 8));
    float sum = 0.f;
#pragma unroll
    for (int j = 0; j < 4; ++j) { f[j] = expf(f[j] - mx); sum += f[j]; }
    sum += __shfl_xor(sum, 1);
    sum += __shfl_xor(sum, 2);
    sum += __shfl_xor(sum, 4);
    sum += __shfl_xor(sum, 8);
    float inv = 1.f / sum;
    if (tx == 0) rowmax[(size_t)b * CC + c0 + c] = mx;
    size_t prow = ((size_t)(b * CC + c0 + c)) * QQ;
#pragma unroll
    for (int j = 0; j < 4; ++j) P[prow + tx + 16 * j] = f[j] * inv;
  }
}

// ---------------------------------------------------------------- q2c: softmax over c of rowmax
__global__ void k_q2c_softmax(const float* __restrict__ rowmax, float* __restrict__ q2cw) {
  int b = blockIdx.x, tid = threadIdx.x;
  __shared__ float rbuf[4], sbuf[4];
  float4 v = *(const float4*)(rowmax + (size_t)b * CC + tid * 4);
  float m = fmaxf(fmaxf(v.x, v.y), fmaxf(v.z, v.w));
  for (int off = 1; off < 64; off <<= 1) m = fmaxf(m, __shfl_xor(m, off));
  int wv = tid >> 6;
  if ((tid & 63) == 0) rbuf[wv] = m;
  __syncthreads();
  m = fmaxf(fmaxf(rbuf[0], rbuf[1]), fmaxf(rbuf[2], rbuf[3]));
  float e0 = expf(v.x - m), e1 = expf(v.y - m), e2 = expf(v.z - m), e3 = expf(v.w - m);
  float sum = e0 + e1 + e2 + e3;
  for (int off = 1; off < 64; off <<= 1) sum += __shfl_xor(sum, off);
  if ((tid & 63) == 0) sbuf[wv] = sum;
  __syncthreads();
  sum = sbuf[0] + sbuf[1] + sbuf[2] + sbuf[3];
  float inv = 1.f / sum;
  float4 o; o.x = e0 * inv; o.y = e1 * inv; o.z = e2 * inv; o.w = e3 * inv;
  *(float4*)(q2cw + (size_t)b * CC + tid * 4) = o;
}

// ---------------------------------------------------------------- q2c_att partials: sum_c w[c]*ctx_bf16[b,c,e]  (ctx from attended block0)
__global__ void k_q2c_part(const unsigned short* __restrict__ att, const float* __restrict__ w,
                           float* __restrict__ part) {
  int b = blockIdx.y, ch = blockIdx.x;
  int e = threadIdx.x;
  const unsigned short* base = att + ((size_t)(b * CC + ch * 128)) * FE + e;
  const float* wp = w + b * CC + ch * 128;
  float acc = 0.f;
#pragma unroll 4
  for (int c = 0; c < 128; ++c) acc += wp[c] * bf2f(base[(size_t)c * FE]);
  part[(b * 8 + ch) * EE + e] = acc;
}

__global__ void k_q2c_sum(const float* __restrict__ part, float* __restrict__ q2catt) {
  int b = blockIdx.x, e = threadIdx.x;
  float a = 0.f;
#pragma unroll
  for (int ch = 0; ch < 8; ++ch) a += part[(b * 8 + ch) * EE + e];
  q2catt[b * EE + e] = a;
}

// ---------------------------------------------------------------- PV + build attended blocks 1-3 (reads bf16 ctx from block0)
__launch_bounds__(256)
__global__ void k_pv(const float* __restrict__ P, const float* __restrict__ question,
                     const float* __restrict__ q2catt, unsigned short* __restrict__ attended) {
  __shared__ float PT[QQ][65];     // P transposed: PT[q][c]
  __shared__ float ql[QQ][68];     // question panel [q][e64]
  const int tid = threadIdx.x;
  const int b = blockIdx.y, c0 = blockIdx.x * 64;
  const int tx = tid & 15, ty = tid >> 4;

  {
    int q4 = (tid & 15) * 4, cb = tid >> 4;
#pragma unroll
    for (int r = 0; r < 4; ++r) {
      int c = cb + 16 * r;
      float4 v = *(const float4*)(P + ((size_t)(b * CC + c0 + c)) * QQ + q4);
      PT[q4 + 0][c] = v.x; PT[q4 + 1][c] = v.y; PT[q4 + 2][c] = v.z; PT[q4 + 3][c] = v.w;
    }
  }
  const float* qb = question + (size_t)b * (QQ * EE);
  const float* g2 = q2catt + b * EE;

  for (int ep = 0; ep < EE; ep += 64) {
    __syncthreads();
    {
      int q = tid >> 2, e16 = (tid & 3) * 16;
      const float* src = qb + (size_t)q * EE + ep + e16;
      float4 v0 = *(const float4*)(src);
      float4 v1 = *(const float4*)(src + 4);
      float4 v2 = *(const float4*)(src + 8);
      float4 v3 = *(const float4*)(src + 12);
      *(float4*)&ql[q][e16]      = v0;
      *(float4*)&ql[q][e16 + 4]  = v1;
      *(float4*)&ql[q][e16 + 8]  = v2;
      *(float4*)&ql[q][e16 + 12] = v3;
    }
    __syncthreads();
    float s[4][4] = {{0.f}};
#pragma unroll 8
    for (int q = 0; q < QQ; ++q) {
      float a0 = PT[q][ty];
      float a1 = PT[q][ty + 16];
      float a2 = PT[q][ty + 32];
      float a3 = PT[q][ty + 48];
      float4 bv = *(const float4*)&ql[q][tx * 4];
      s[0][0] += a0 * bv.x; s[0][1] += a0 * bv.y; s[0][2] += a0 * bv.z; s[0][3] += a0 * bv.w;
      s[1][0] += a1 * bv.x; s[1][1] += a1 * bv.y; s[1][2] += a1 * bv.z; s[1][3] += a1 * bv.w;
      s[2][0] += a2 * bv.x; s[2][1] += a2 * bv.y; s[2][2] += a2 * bv.z; s[2][3] += a2 * bv.w;
      s[3][0] += a3 * bv.x; s[3][1] += a3 * bv.y; s[3][2] += a3 * bv.z; s[3][3] += a3 * bv.w;
    }
    float4 gv = *(const float4*)(g2 + ep + tx * 4);
#pragma unroll
    for (int i = 0; i < 4; ++i) {
      int c = ty + 16 * i;
      size_t row = (size_t)(b * CC + c0 + c);
      unsigned short* arow = attended + row * (size_t)FE;
      ushort4 cu = *(const ushort4*)(arow + 0 * EE + ep + tx * 4);
      float cx = bf2f(cu.x), cy = bf2f(cu.y), cz = bf2f(cu.z), cw = bf2f(cu.w);
      ushort4 s1, s2, s3;
      s1.x = f2bf(s[i][0]);        s1.y = f2bf(s[i][1]);        s1.z = f2bf(s[i][2]);        s1.w = f2bf(s[i][3]);
      s2.x = f2bf(cx * s[i][0]);   s2.y = f2bf(cy * s[i][1]);   s2.z = f2bf(cz * s[i][2]);   s2.w = f2bf(cw * s[i][3]);
      s3.x = f2bf(cx * gv.x);      s3.y = f2bf(cy * gv.y);      s3.z = f2bf(cz * gv.z);      s3.w = f2bf(cw * gv.w);
      *(ushort4*)(arow + 1 * EE + ep + tx * 4) = s1;
      *(ushort4*)(arow + 2 * EE + ep + tx * 4) = s2;
      *(ushort4*)(arow + 3 * EE + ep + tx * 4) = s3;
    }
  }
}

// ---------------------------------------------------------------- final GEMM: out = attended @ W^T + b, masked
// 256x256 tile, BK=64, 8 waves (2Mx4N), 8-phase schedule with counted vmcnt,
// compiler-counted lgkm waits (no manual lgkmcnt(0) drain), XOR-swizzled LDS,
// XCD-chunked block swizzle.
__launch_bounds__(512, 2)
__global__ void k_gemm(const unsigned short* __restrict__ A, const unsigned short* __restrict__ Bw,
                       const float* __restrict__ bias, const float* __restrict__ mask,
                       float* __restrict__ out) {
  // [slot][half 128-rows][row][k64]
  __shared__ bf16_t As[2][2][128][64];
  __shared__ bf16_t Bs[2][2][128][64];
  const int tid = threadIdx.x;
  const int lane = tid & 63;
  const int wave = tid >> 6;          // 0..7
  const int wr = wave >> 2;           // 0..1 (M half)
  const int wc = wave & 3;            // 0..3 (N quarter)
  const int bh = wc >> 1;             // B half this wave reads

  // XCD-chunked swizzle: 512 blocks, 8 XCDs -> 64 consecutive wgs per XCD.
  const int bid = blockIdx.x;
  const int wg = (bid & 7) * 64 + (bid >> 3);
  const int brow = (wg >> 2) * 256;
  const int bcol = (wg & 3) * 256;

  const int r = lane & 15, kg4 = lane >> 4;
  const int rx = r & 7;               // read-side XOR key

  // staging geometry: half-tile = 128 rows x 64 k. 512 thr x 2 loads x 16B.
  const int srow = tid >> 3;                  // 0..63 (rows srow, srow+64)
  const int sg = (tid & 7) ^ (srow & 7);      // pre-swizzled source granule
  const unsigned short* gAb = A  + (size_t)(brow + srow) * FE + sg * 8;
  const unsigned short* gBb = Bw + (size_t)(bcol + srow) * FE + sg * 8;
  bf16_t* ldsAb = &As[0][0][srow][(tid & 7) * 8];
  bf16_t* ldsBb = &Bs[0][0][srow][(tid & 7) * 8];

  f32x4 acc[8][4] = {};
  bf16x8 faA[4][2], faB[4][2], fbA[2][2], fbB[2][2];

#define BARX __builtin_amdgcn_s_barrier()
#define VMW4 asm volatile("s_waitcnt vmcnt(4)" ::: "memory")
#define VMW0 asm volatile("s_waitcnt vmcnt(0)" ::: "memory")

#define ST_A(SLOT, H, KOFF) do {                                              \
    const unsigned short* s_ = gAb + (size_t)((H) * 128) * FE + (KOFF);       \
    bf16_t* d_ = ldsAb + ((SLOT) * 2 + (H)) * (128 * 64);                     \
    gload_lds16(s_, d_);                                                      \
    gload_lds16(s_ + (size_t)64 * FE, d_ + 64 * 64);                          \
  } while (0)
#define ST_B(SLOT, H, KOFF) do {                                              \
    const unsigned short* s_ = gBb + (size_t)((H) * 128) * FE + (KOFF);       \
    bf16_t* d_ = ldsBb + ((SLOT) * 2 + (H)) * (128 * 64);                     \
    gload_lds16(s_, d_);                                                      \
    gload_lds16(s_ + (size_t)64 * FE, d_ + 64 * 64);                          \
  } while (0)

#define RD_FA(DST, SLOT, MB) do {                                             \
    _Pragma("unroll") for (int mm = 0; mm < 4; ++mm) {                        \
      const int row_ = ((MB) + mm) * 16 + r;                                  \
      _Pragma("unroll") for (int ks = 0; ks < 2; ++ks)                        \
        DST[mm][ks] = *(const bf16x8*)&As[SLOT][wr][row_][((ks * 4 + kg4) ^ rx) * 8]; \
    } } while (0)
#define RD_FB(DST, SLOT, NB) do {                                             \
    _Pragma("unroll") for (int nn = 0; nn < 2; ++nn) {                        \
      const int row_ = (wc & 1) * 64 + ((NB) + nn) * 16 + r;                  \
      _Pragma("unroll") for (int ks = 0; ks < 2; ++ks)                        \
        DST[nn][ks] = *(const bf16x8*)&Bs[SLOT][bh][row_][((ks * 4 + kg4) ^ rx) * 8]; \
    } } while (0)

#define MFMA16(FA, FB, MB, NB) do {                                           \
    __builtin_amdgcn_s_setprio(1);                                            \
    _Pragma("unroll") for (int ks = 0; ks < 2; ++ks)                          \
    _Pragma("unroll") for (int mm = 0; mm < 4; ++mm)                          \
    _Pragma("unroll") for (int nn = 0; nn < 2; ++nn)                          \
      acc[(MB) + mm][(NB) + nn] = __builtin_amdgcn_mfma_f32_16x16x32_bf16(    \
          FA[mm][ks], FB[nn][ks], acc[(MB) + mm][(NB) + nn], 0, 0, 0);        \
    __builtin_amdgcn_s_setprio(0);                                            \
  } while (0)

  // Prologue: t0 (B0,B1,A0,A1) + t1 (B0,B1). Wait for t0 (keep t1-B 4 loads in flight).
  ST_B(0, 0, 0);  ST_B(0, 1, 0);  ST_A(0, 0, 0);  ST_A(0, 1, 0);
  ST_B(1, 0, 64); ST_B(1, 1, 64);
  VMW4;
  BARX;

#pragma unroll 1
  for (int i = 0; i < 8; ++i) {
    const int kT1 = (2 * i + 1) * 64;
    const int kT2 = (2 * i + 2) * 64;
    const int kT3 = (2 * i + 3) * 64;
    const bool more = (i < 7);

    // ---- K-tile t0 = 2i (slot 0) ----
    // ph1
    RD_FA(faA, 0, 0); RD_FB(fbA, 0, 0);
    ST_A(1, 0, kT1);
    BARX; MFMA16(faA, fbA, 0, 0); BARX;
    // ph2
    RD_FB(fbB, 0, 2);
    ST_A(1, 1, kT1);
    BARX; MFMA16(faA, fbB, 0, 2); BARX;
    // ph3
    RD_FA(faB, 0, 4);
    if (more) ST_B(0, 0, kT2);
    BARX; MFMA16(faB, fbA, 4, 0); BARX;
    // ph4
    if (more) { ST_B(0, 1, kT2); VMW4; } else { VMW0; }
    BARX; MFMA16(faB, fbB, 4, 2); BARX;

    // ---- K-tile t1 = 2i+1 (slot 1) ----
    // ph5
    RD_FA(faA, 1, 0); RD_FB(fbA, 1, 0);
    if (more) ST_A(0, 0, kT2);
    BARX; MFMA16(faA, fbA, 0, 0); BARX;
    // ph6
    RD_FB(fbB, 1, 2);
    if (more) ST_A(0, 1, kT2);
    BARX; MFMA16(faA, fbB, 0, 2); BARX;
    // ph7
    RD_FA(faB, 1, 4);
    if (more) ST_B(1, 0, kT3);
    BARX; MFMA16(faB, fbA, 4, 0); BARX;
    // ph8
    if (more) { ST_B(1, 1, kT3); VMW4; }
    BARX; MFMA16(faB, fbB, 4, 2); BARX;
  }
#undef ST_A
#undef ST_B
#undef RD_FA
#undef RD_FB
#undef MFMA16

#pragma unroll
  for (int m = 0; m < 8; ++m) {
#pragma unroll
    for (int n = 0; n < 4; ++n) {
#pragma unroll
      for (int reg = 0; reg < 4; ++reg) {
        int row = brow + wr * 128 + m * 16 + kg4 * 4 + reg;
        int col = bcol + wc * 64 + n * 16 + r;
        out[(size_t)row * FE + col] = (acc[m][n][reg] + bias[col]) * mask[row];
      }
    }
  }
}

// ---------------------------------------------------------------- launch
extern "C" void kernel_launch(void* const* d_in, const int* in_sizes, int n_in,
                              void* d_out, int out_size, void* d_ws, size_t ws_size,
                              hipStream_t stream) {
  const float* ctx  = (const float*)d_in[0];
  const float* ques = (const float*)d_in[1];
  const float* mask = (const float*)d_in[2];
  const float* w_q  = (const float*)d_in[3];
  const float* w_c  = (const float*)d_in[4];
  const float* w_m  = (const float*)d_in[5];
  const float* fW   = (const float*)d_in[6];
  const float* fb   = (const float*)d_in[7];
  float* out = (float*)d_out;

  char* ws = (char*)d_ws;
  float* qm     = (float*)(ws);                       // 8,388,608 B
  float* qw     = (float*)(ws + 8388608);             // 8,192 B
  float* rowmax = (float*)(ws + 8396800);             // 131,072 B
  float* q2cw   = (float*)(ws + 8527872);             // 131,072 B
  float* part   = (float*)(ws + 8658944);             // 262,144 B
  float* q2catt = (float*)(ws + 8921088);             // 32,768 B
  float* P      = (float*)(ws + 8953856);             // 8,388,608 B
  unsigned short* attended = (unsigned short*)(ws + 17342464);  // 67,108,864 B
  unsigned short* Wb       = (unsigned short*)(ws + 84451328);  // 2,097,152 B

  k_prep<<<1536, 256, 0, stream>>>(ques, w_q, w_m, qm, qw, fW, Wb);
  k_sim<<<dim3(16, 32), 256, 0, stream>>>(ctx, qm, qw, w_c, P, rowmax, attended);
  k_q2c_softmax<<<32, 256, 0, stream>>>(rowmax, q2cw);
  k_q2c_part<<<dim3(8, 32), 256, 0, stream>>>(attended, q2cw, part);
  k_q2c_sum<<<32, 256, 0, stream>>>(part, q2catt);
  k_pv<<<dim3(16, 32), 256, 0, stream>>>(P, ques, q2catt, attended);
  k_gemm<<<512, 512, 0, stream>>>(attended, Wb, fb, mask, out);
}

// Round 7
// 160.666 us; speedup vs baseline: 1.1465x; 1.1465x over previous
//
#include <hip/hip_runtime.h>

// Problem constants
#define BB 32
#define CC 1024
#define QQ 64
#define EE 256
#define FE 1024
#define MM (BB*CC)   // 32768

typedef __bf16 bf16_t;
typedef bf16_t bf16x8 __attribute__((ext_vector_type(8)));
typedef float f32x4 __attribute__((ext_vector_type(4)));
typedef unsigned short u16x8 __attribute__((ext_vector_type(8)));

__device__ __forceinline__ unsigned short f2bf(float f) {
  unsigned u = __float_as_uint(f);
  u += 0x7fffu + ((u >> 16) & 1u);   // RNE
  return (unsigned short)(u >> 16);
}
__device__ __forceinline__ float bf2f(unsigned short u) {
  return __uint_as_float(((unsigned)u) << 16);
}

__device__ __forceinline__ void gload_lds16(const void* g, void* l) {
  __builtin_amdgcn_global_load_lds(
      (const __attribute__((address_space(1))) unsigned int*)g,
      (__attribute__((address_space(3))) unsigned int*)l, 16, 0, 0);
}

// ---------------------------------------------------------------- prep: qw = question.w_question; cast W to bf16
__global__ void k_prep(const float* __restrict__ question, const float* __restrict__ w_question,
                       float* __restrict__ qw,
                       const float* __restrict__ W, unsigned short* __restrict__ Wb) {
  int bx = blockIdx.x;
  if (bx < 512) {
    int gid = bx * 256 + threadIdx.x;
    int row = gid >> 6;            // (b*QQ + q), 0..2047
    int lane = gid & 63;
    const float4 q = *(const float4*)(question + (size_t)row * EE + lane * 4);
    const float4 wq = *(const float4*)(w_question + lane * 4);
    float d = q.x*wq.x + q.y*wq.y + q.z*wq.z + q.w*wq.w;
    d += __shfl_xor(d, 1);  d += __shfl_xor(d, 2);  d += __shfl_xor(d, 4);
    d += __shfl_xor(d, 8);  d += __shfl_xor(d, 16); d += __shfl_xor(d, 32);
    if (lane == 0) qw[row] = d;
  } else {
    int i = ((bx - 512) * 256 + threadIdx.x) * 4;
    float4 v = *(const float4*)(W + i);
    ushort4 o; o.x = f2bf(v.x); o.y = f2bf(v.y); o.z = f2bf(v.z); o.w = f2bf(v.w);
    *(ushort4*)(Wb + i) = o;
  }
}

#define DOT4(acc, A, Bv) acc += A.x*Bv.x + A.y*Bv.y + A.z*Bv.z + A.w*Bv.w

// ---------------------------------------------------------------- fused similarity + softmax + PV
// Writes: att block0 = bf16(ctx), block1 = c2q, block2 = ctx*c2q, rowmax.
// P lives only in LDS (bf16). question buffer reused: sim halves [64][132], PV panels [64][68].
__launch_bounds__(256)
__global__ void k_simpv(const float* __restrict__ ctx, const float* __restrict__ question,
                        const float* __restrict__ qw_g, const float* __restrict__ w_context,
                        const float* __restrict__ w_multiple,
                        float* __restrict__ rowmax, unsigned short* __restrict__ att) {
  __shared__ float qbuf[QQ * 132];          // 33.8 KB (sim: [q][128+4]; PV: [q][64+4])
  __shared__ float ck[64][36];              // ctx*w_mult chunk
  __shared__ unsigned short Pl[QQ][68];     // P[q][c] bf16
  __shared__ float cwl[64];
  __shared__ float qwl[QQ];
  const int tid = threadIdx.x;
  const int b = blockIdx.y;
  const int c0 = blockIdx.x * 64;
  const int tx = tid & 15, ty = tid >> 4;

  const float* qb = question + (size_t)b * (QQ * EE);
  if (tid < QQ) qwl[tid] = qw_g[b * QQ + tid];

  const int cr = tid >> 3, er = (tid & 7) * 4;
  const float* crow0 = ctx + ((size_t)(b * CC + c0 + cr)) * EE;
  const float* crow1 = crow0 + 32 * EE;
  unsigned short* arow0 = att + ((size_t)(b * CC + c0 + cr)) * FE;
  unsigned short* arow1 = arow0 + (size_t)32 * FE;
  float s[4][4] = {{0.f}};
  float cp0 = 0.f, cp1 = 0.f;

  // ---------- similarity over two e-halves ----------
  for (int h = 0; h < 2; ++h) {
    if (h) __syncthreads();          // all dots on previous half done before restage
    for (int idx = tid * 4; idx < QQ * 128; idx += 1024) {
      int row = idx >> 7, col = idx & 127;
      *(float4*)&qbuf[row * 132 + col] = *(const float4*)(qb + (size_t)row * EE + h * 128 + col);
    }
    for (int eo2 = 0; eo2 < 128; eo2 += 32) {
      const int eo = h * 128 + eo2;
      float4 cv0 = *(const float4*)(crow0 + eo + er);
      float4 cv1 = *(const float4*)(crow1 + eo + er);
      float4 wc = *(const float4*)(w_context + eo + er);
      float4 wm = *(const float4*)(w_multiple + eo + er);
      cp0 += cv0.x*wc.x + cv0.y*wc.y + cv0.z*wc.z + cv0.w*wc.w;
      cp1 += cv1.x*wc.x + cv1.y*wc.y + cv1.z*wc.z + cv1.w*wc.w;
      // attended block0 = bf16(ctx)
      ushort4 u0, u1;
      u0.x = f2bf(cv0.x); u0.y = f2bf(cv0.y); u0.z = f2bf(cv0.z); u0.w = f2bf(cv0.w);
      u1.x = f2bf(cv1.x); u1.y = f2bf(cv1.y); u1.z = f2bf(cv1.z); u1.w = f2bf(cv1.w);
      *(ushort4*)(arow0 + eo + er) = u0;
      *(ushort4*)(arow1 + eo + er) = u1;
      __syncthreads();               // covers qbuf staging (first iter) / prior dot reads
      float4 m0, m1;
      m0.x = cv0.x*wm.x; m0.y = cv0.y*wm.y; m0.z = cv0.z*wm.z; m0.w = cv0.w*wm.w;
      m1.x = cv1.x*wm.x; m1.y = cv1.y*wm.y; m1.z = cv1.z*wm.z; m1.w = cv1.w*wm.w;
      *(float4*)&ck[cr][er] = m0;
      *(float4*)&ck[cr + 32][er] = m1;
      __syncthreads();
#pragma unroll
      for (int ee = 0; ee < 32; ee += 4) {
        float4 a0 = *(const float4*)&ck[ty +  0][ee];
        float4 a1 = *(const float4*)&ck[ty + 16][ee];
        float4 a2 = *(const float4*)&ck[ty + 32][ee];
        float4 a3 = *(const float4*)&ck[ty + 48][ee];
        float4 b0 = *(const float4*)&qbuf[(tx +  0) * 132 + eo2 + ee];
        float4 b1 = *(const float4*)&qbuf[(tx + 16) * 132 + eo2 + ee];
        float4 b2 = *(const float4*)&qbuf[(tx + 32) * 132 + eo2 + ee];
        float4 b3 = *(const float4*)&qbuf[(tx + 48) * 132 + eo2 + ee];
        DOT4(s[0][0], a0, b0); DOT4(s[0][1], a0, b1); DOT4(s[0][2], a0, b2); DOT4(s[0][3], a0, b3);
        DOT4(s[1][0], a1, b0); DOT4(s[1][1], a1, b1); DOT4(s[1][2], a1, b2); DOT4(s[1][3], a1, b3);
        DOT4(s[2][0], a2, b0); DOT4(s[2][1], a2, b1); DOT4(s[2][2], a2, b2); DOT4(s[2][3], a2, b3);
        DOT4(s[3][0], a3, b0); DOT4(s[3][1], a3, b1); DOT4(s[3][2], a3, b2); DOT4(s[3][3], a3, b3);
      }
    }
  }
  // cw reduce (8 lanes per row)
  cp0 += __shfl_xor(cp0, 1); cp0 += __shfl_xor(cp0, 2); cp0 += __shfl_xor(cp0, 4);
  cp1 += __shfl_xor(cp1, 1); cp1 += __shfl_xor(cp1, 2); cp1 += __shfl_xor(cp1, 4);
  if ((tid & 7) == 0) { cwl[cr] = cp0; cwl[cr + 32] = cp1; }
  __syncthreads();

  // ---------- softmax per row -> Pl (bf16, [q][c]), rowmax ----------
#pragma unroll
  for (int i = 0; i < 4; ++i) {
    int c = ty + 16 * i;
    float cw = cwl[c];
    float f[4], mx = -1e30f;
#pragma unroll
    for (int j = 0; j < 4; ++j) {
      f[j] = s[i][j] + cw + qwl[tx + 16 * j];
      mx = fmaxf(mx, f[j]);
    }
    mx = fmaxf(mx, __shfl_xor(mx, 1));
    mx = fmaxf(mx, __shfl_xor(mx, 2));
    mx = fmaxf(mx, __shfl_xor(mx, 4));
    mx = fmaxf(mx, __shfl_xor(mx, 8));
    float sum = 0.f;
#pragma unroll
    for (int j = 0; j < 4; ++j) { f[j] = expf(f[j] - mx); sum += f[j]; }
    sum += __shfl_xor(sum, 1);
    sum += __shfl_xor(sum, 2);
    sum += __shfl_xor(sum, 4);
    sum += __shfl_xor(sum, 8);
    float inv = 1.f / sum;
    if (tx == 0) rowmax[(size_t)b * CC + c0 + c] = mx;
#pragma unroll
    for (int j = 0; j < 4; ++j) Pl[tx + 16 * j][c] = f2bf(f[j] * inv);
  }
  __syncthreads();   // Pl visible; qbuf free for PV panels

  // ---------- PV: c2q = P @ question; write att1, att2 ----------
  for (int ep = 0; ep < EE; ep += 64) {
    if (ep) __syncthreads();
    {
      int q = tid >> 2, e16 = (tid & 3) * 16;
      const float* src = qb + (size_t)q * EE + ep + e16;
      *(float4*)&qbuf[q * 68 + e16 +  0] = *(const float4*)(src);
      *(float4*)&qbuf[q * 68 + e16 +  4] = *(const float4*)(src + 4);
      *(float4*)&qbuf[q * 68 + e16 +  8] = *(const float4*)(src + 8);
      *(float4*)&qbuf[q * 68 + e16 + 12] = *(const float4*)(src + 12);
    }
    __syncthreads();
    float s2[4][4] = {{0.f}};
#pragma unroll 8
    for (int q = 0; q < QQ; ++q) {
      float a0 = bf2f(Pl[q][ty +  0]);
      float a1 = bf2f(Pl[q][ty + 16]);
      float a2 = bf2f(Pl[q][ty + 32]);
      float a3 = bf2f(Pl[q][ty + 48]);
      float4 bv = *(const float4*)&qbuf[q * 68 + tx * 4];
      s2[0][0] += a0 * bv.x; s2[0][1] += a0 * bv.y; s2[0][2] += a0 * bv.z; s2[0][3] += a0 * bv.w;
      s2[1][0] += a1 * bv.x; s2[1][1] += a1 * bv.y; s2[1][2] += a1 * bv.z; s2[1][3] += a1 * bv.w;
      s2[2][0] += a2 * bv.x; s2[2][1] += a2 * bv.y; s2[2][2] += a2 * bv.z; s2[2][3] += a2 * bv.w;
      s2[3][0] += a3 * bv.x; s2[3][1] += a3 * bv.y; s2[3][2] += a3 * bv.z; s2[3][3] += a3 * bv.w;
    }
#pragma unroll
    for (int i = 0; i < 4; ++i) {
      int c = ty + 16 * i;
      size_t row = (size_t)(b * CC + c0 + c);
      unsigned short* arow = att + row * (size_t)FE;
      ushort4 cu = *(const ushort4*)(arow + ep + tx * 4);   // att0 (L2-hot, same block wrote it)
      float cx = bf2f(cu.x), cy = bf2f(cu.y), cz = bf2f(cu.z), cw = bf2f(cu.w);
      ushort4 o1, o2;
      o1.x = f2bf(s2[i][0]);       o1.y = f2bf(s2[i][1]);       o1.z = f2bf(s2[i][2]);       o1.w = f2bf(s2[i][3]);
      o2.x = f2bf(cx * s2[i][0]);  o2.y = f2bf(cy * s2[i][1]);  o2.z = f2bf(cz * s2[i][2]);  o2.w = f2bf(cw * s2[i][3]);
      *(ushort4*)(arow + 1 * EE + ep + tx * 4) = o1;
      *(ushort4*)(arow + 2 * EE + ep + tx * 4) = o2;
    }
  }
}

// ---------------------------------------------------------------- q2c: softmax over c of rowmax
__global__ void k_q2c_softmax(const float* __restrict__ rowmax, float* __restrict__ q2cw) {
  int b = blockIdx.x, tid = threadIdx.x;
  __shared__ float rbuf[4], sbuf[4];
  float4 v = *(const float4*)(rowmax + (size_t)b * CC + tid * 4);
  float m = fmaxf(fmaxf(v.x, v.y), fmaxf(v.z, v.w));
  for (int off = 1; off < 64; off <<= 1) m = fmaxf(m, __shfl_xor(m, off));
  int wv = tid >> 6;
  if ((tid & 63) == 0) rbuf[wv] = m;
  __syncthreads();
  m = fmaxf(fmaxf(rbuf[0], rbuf[1]), fmaxf(rbuf[2], rbuf[3]));
  float e0 = expf(v.x - m), e1 = expf(v.y - m), e2 = expf(v.z - m), e3 = expf(v.w - m);
  float sum = e0 + e1 + e2 + e3;
  for (int off = 1; off < 64; off <<= 1) sum += __shfl_xor(sum, off);
  if ((tid & 63) == 0) sbuf[wv] = sum;
  __syncthreads();
  sum = sbuf[0] + sbuf[1] + sbuf[2] + sbuf[3];
  float inv = 1.f / sum;
  float4 o; o.x = e0 * inv; o.y = e1 * inv; o.z = e2 * inv; o.w = e3 * inv;
  *(float4*)(q2cw + (size_t)b * CC + tid * 4) = o;
}

// ---------------------------------------------------------------- q2c_att partials: sum_c w[c]*ctx_bf16[b,c,e]
__global__ void k_q2c_part(const unsigned short* __restrict__ att, const float* __restrict__ w,
                           float* __restrict__ part) {
  int b = blockIdx.y, ch = blockIdx.x;
  int e = threadIdx.x;
  const unsigned short* base = att + ((size_t)(b * CC + ch * 128)) * FE + e;
  const float* wp = w + b * CC + ch * 128;
  float acc = 0.f;
#pragma unroll 4
  for (int c = 0; c < 128; ++c) acc += wp[c] * bf2f(base[(size_t)c * FE]);
  part[(b * 8 + ch) * EE + e] = acc;
}

__global__ void k_q2c_sum(const float* __restrict__ part, float* __restrict__ q2catt) {
  int b = blockIdx.x, e = threadIdx.x;
  float a = 0.f;
#pragma unroll
  for (int ch = 0; ch < 8; ++ch) a += part[(b * 8 + ch) * EE + e];
  q2catt[b * EE + e] = a;
}

// ---------------------------------------------------------------- att3 = bf16(ctx_bf16 * q2catt)
__global__ void k_att3(const unsigned short* __restrict__ att_ro, const float* __restrict__ q2catt,
                       unsigned short* __restrict__ att_wr) {
  int unit = blockIdx.x * 256 + threadIdx.x;     // 32768 rows * 32 chunks
  int row = unit >> 5;
  int e8 = (unit & 31) * 8;
  int b = row >> 10;
  u16x8 c = *(const u16x8*)(att_ro + (size_t)row * FE + e8);
  float4 g0 = *(const float4*)(q2catt + b * EE + e8);
  float4 g1 = *(const float4*)(q2catt + b * EE + e8 + 4);
  u16x8 o;
  o[0] = f2bf(bf2f(c[0]) * g0.x); o[1] = f2bf(bf2f(c[1]) * g0.y);
  o[2] = f2bf(bf2f(c[2]) * g0.z); o[3] = f2bf(bf2f(c[3]) * g0.w);
  o[4] = f2bf(bf2f(c[4]) * g1.x); o[5] = f2bf(bf2f(c[5]) * g1.y);
  o[6] = f2bf(bf2f(c[6]) * g1.z); o[7] = f2bf(bf2f(c[7]) * g1.w);
  *(u16x8*)(att_wr + (size_t)row * FE + 3 * EE + e8) = o;
}

// ---------------------------------------------------------------- final GEMM (unchanged from R6)
__launch_bounds__(512, 2)
__global__ void k_gemm(const unsigned short* __restrict__ A, const unsigned short* __restrict__ Bw,
                       const float* __restrict__ bias, const float* __restrict__ mask,
                       float* __restrict__ out) {
  __shared__ bf16_t As[2][2][128][64];
  __shared__ bf16_t Bs[2][2][128][64];
  const int tid = threadIdx.x;
  const int lane = tid & 63;
  const int wave = tid >> 6;
  const int wr = wave >> 2;
  const int wc = wave & 3;
  const int bh = wc >> 1;

  const int bid = blockIdx.x;
  const int wg = (bid & 7) * 64 + (bid >> 3);
  const int brow = (wg >> 2) * 256;
  const int bcol = (wg & 3) * 256;

  const int r = lane & 15, kg4 = lane >> 4;
  const int rx = r & 7;

  const int srow = tid >> 3;
  const int sg = (tid & 7) ^ (srow & 7);
  const unsigned short* gAb = A  + (size_t)(brow + srow) * FE + sg * 8;
  const unsigned short* gBb = Bw + (size_t)(bcol + srow) * FE + sg * 8;
  bf16_t* ldsAb = &As[0][0][srow][(tid & 7) * 8];
  bf16_t* ldsBb = &Bs[0][0][srow][(tid & 7) * 8];

  f32x4 acc[8][4] = {};
  bf16x8 faA[4][2], faB[4][2], fbA[2][2], fbB[2][2];

#define BARX __builtin_amdgcn_s_barrier()
#define VMW4 asm volatile("s_waitcnt vmcnt(4)" ::: "memory")
#define VMW0 asm volatile("s_waitcnt vmcnt(0)" ::: "memory")

#define ST_A(SLOT, H, KOFF) do {                                              \
    const unsigned short* s_ = gAb + (size_t)((H) * 128) * FE + (KOFF);       \
    bf16_t* d_ = ldsAb + ((SLOT) * 2 + (H)) * (128 * 64);                     \
    gload_lds16(s_, d_);                                                      \
    gload_lds16(s_ + (size_t)64 * FE, d_ + 64 * 64);                          \
  } while (0)
#define ST_B(SLOT, H, KOFF) do {                                              \
    const unsigned short* s_ = gBb + (size_t)((H) * 128) * FE + (KOFF);       \
    bf16_t* d_ = ldsBb + ((SLOT) * 2 + (H)) * (128 * 64);                     \
    gload_lds16(s_, d_);                                                      \
    gload_lds16(s_ + (size_t)64 * FE, d_ + 64 * 64);                          \
  } while (0)

#define RD_FA(DST, SLOT, MB) do {                                             \
    _Pragma("unroll") for (int mm = 0; mm < 4; ++mm) {                        \
      const int row_ = ((MB) + mm) * 16 + r;                                  \
      _Pragma("unroll") for (int ks = 0; ks < 2; ++ks)                        \
        DST[mm][ks] = *(const bf16x8*)&As[SLOT][wr][row_][((ks * 4 + kg4) ^ rx) * 8]; \
    } } while (0)
#define RD_FB(DST, SLOT, NB) do {                                             \
    _Pragma("unroll") for (int nn = 0; nn < 2; ++nn) {                        \
      const int row_ = (wc & 1) * 64 + ((NB) + nn) * 16 + r;                  \
      _Pragma("unroll") for (int ks = 0; ks < 2; ++ks)                        \
        DST[nn][ks] = *(const bf16x8*)&Bs[SLOT][bh][row_][((ks * 4 + kg4) ^ rx) * 8]; \
    } } while (0)

#define MFMA16(FA, FB, MB, NB) do {                                           \
    __builtin_amdgcn_s_setprio(1);                                            \
    _Pragma("unroll") for (int ks = 0; ks < 2; ++ks)                          \
    _Pragma("unroll") for (int mm = 0; mm < 4; ++mm)                          \
    _Pragma("unroll") for (int nn = 0; nn < 2; ++nn)                          \
      acc[(MB) + mm][(NB) + nn] = __builtin_amdgcn_mfma_f32_16x16x32_bf16(    \
          FA[mm][ks], FB[nn][ks], acc[(MB) + mm][(NB) + nn], 0, 0, 0);        \
    __builtin_amdgcn_s_setprio(0);                                            \
  } while (0)

  ST_B(0, 0, 0);  ST_B(0, 1, 0);  ST_A(0, 0, 0);  ST_A(0, 1, 0);
  ST_B(1, 0, 64); ST_B(1, 1, 64);
  VMW4;
  BARX;

#pragma unroll 1
  for (int i = 0; i < 8; ++i) {
    const int kT1 = (2 * i + 1) * 64;
    const int kT2 = (2 * i + 2) * 64;
    const int kT3 = (2 * i + 3) * 64;
    const bool more = (i < 7);

    RD_FA(faA, 0, 0); RD_FB(fbA, 0, 0);
    ST_A(1, 0, kT1);
    BARX; MFMA16(faA, fbA, 0, 0); BARX;
    RD_FB(fbB, 0, 2);
    ST_A(1, 1, kT1);
    BARX; MFMA16(faA, fbB, 0, 2); BARX;
    RD_FA(faB, 0, 4);
    if (more) ST_B(0, 0, kT2);
    BARX; MFMA16(faB, fbA, 4, 0); BARX;
    if (more) { ST_B(0, 1, kT2); VMW4; } else { VMW0; }
    BARX; MFMA16(faB, fbB, 4, 2); BARX;

    RD_FA(faA, 1, 0); RD_FB(fbA, 1, 0);
    if (more) ST_A(0, 0, kT2);
    BARX; MFMA16(faA, fbA, 0, 0); BARX;
    RD_FB(fbB, 1, 2);
    if (more) ST_A(0, 1, kT2);
    BARX; MFMA16(faA, fbB, 0, 2); BARX;
    RD_FA(faB, 1, 4);
    if (more) ST_B(1, 0, kT3);
    BARX; MFMA16(faB, fbA, 4, 0); BARX;
    if (more) { ST_B(1, 1, kT3); VMW4; }
    BARX; MFMA16(faB, fbB, 4, 2); BARX;
  }
#undef ST_A
#undef ST_B
#undef RD_FA
#undef RD_FB
#undef MFMA16

#pragma unroll
  for (int m = 0; m < 8; ++m) {
#pragma unroll
    for (int n = 0; n < 4; ++n) {
#pragma unroll
      for (int reg = 0; reg < 4; ++reg) {
        int row = brow + wr * 128 + m * 16 + kg4 * 4 + reg;
        int col = bcol + wc * 64 + n * 16 + r;
        out[(size_t)row * FE + col] = (acc[m][n][reg] + bias[col]) * mask[row];
      }
    }
  }
}

// ---------------------------------------------------------------- launch
extern "C" void kernel_launch(void* const* d_in, const int* in_sizes, int n_in,
                              void* d_out, int out_size, void* d_ws, size_t ws_size,
                              hipStream_t stream) {
  const float* ctx  = (const float*)d_in[0];
  const float* ques = (const float*)d_in[1];
  const float* mask = (const float*)d_in[2];
  const float* w_q  = (const float*)d_in[3];
  const float* w_c  = (const float*)d_in[4];
  const float* w_m  = (const float*)d_in[5];
  const float* fW   = (const float*)d_in[6];
  const float* fb   = (const float*)d_in[7];
  float* out = (float*)d_out;

  char* ws = (char*)d_ws;
  float* qw     = (float*)(ws);                        //     8,192 B
  float* rowmax = (float*)(ws + 8192);                 //   131,072 B
  float* q2cw   = (float*)(ws + 139264);               //   131,072 B
  float* part   = (float*)(ws + 270336);               //   262,144 B
  float* q2catt = (float*)(ws + 532480);               //    32,768 B
  unsigned short* attended = (unsigned short*)(ws + 1048576);   // 67,108,864 B
  unsigned short* Wb       = (unsigned short*)(ws + 68157440);  //  2,097,152 B

  k_prep<<<1536, 256, 0, stream>>>(ques, w_q, qw, fW, Wb);
  k_simpv<<<dim3(16, 32), 256, 0, stream>>>(ctx, ques, qw, w_c, w_m, rowmax, attended);
  k_q2c_softmax<<<32, 256, 0, stream>>>(rowmax, q2cw);
  k_q2c_part<<<dim3(8, 32), 256, 0, stream>>>(attended, q2cw, part);
  k_q2c_sum<<<32, 256, 0, stream>>>(part, q2catt);
  k_att3<<<4096, 256, 0, stream>>>(attended, q2catt, attended);
  k_gemm<<<512, 512, 0, stream>>>(attended, Wb, fb, mask, out);
}